// Round 17
// baseline (488.389 us; speedup 1.0000x reference)
//
#include <hip/hip_runtime.h>
#include <math.h>

#define NB 2
#define NY 360
#define NX 720
#define NZ 32
#define NPTS (NB*NY*NX*NZ)     // 16,588,800
#define NCOL (NB*NY*NX)        // 518,400

__device__ __forceinline__ int i4(int b,int y,int x,int z){ return (((b*NY)+y)*NX+x)*NZ+z; }
__device__ __forceinline__ int i3(int b,int y,int x){ return ((b*NY)+y)*NX+x; }

#define F_RAD   6371000.0f
#define F_OMEGA 7.292e-5f
#define F_CP    1004.0f
#define F_DLAT  ((float)(M_PI/360.0))                 /* == dlon */
#define F_DYR   ((float)(M_PI/360.0*6371000.0))      /* dlat*RAD */
#define F_HPI   ((float)(M_PI/2.0))
#define TH      ((float)(2.0*M_PI/720.0))

// -------------------- kernel 1: div_h (float4 over z) --------------------
__global__ __launch_bounds__(256) void k_divh(const float* __restrict__ u,
                                              const float* __restrict__ v,
                                              float* __restrict__ divh) {
  const int bswz = (blockIdx.x & 7) * 2025 + (blockIdx.x >> 3);
  const int idx = bswz*256 + threadIdx.x;          // quad index: NPTS/4 total
  const int zq = idx & 7;
  const int x  = (idx >> 3) % NX;
  const int by = idx / (NX*8);
  const int y  = by % NY;
  const int b  = by / NY;
  const float lat = -F_HPI + (y+0.5f)*F_DLAT;
  const float cl  = cosf(lat);
  const float invdx = 0.5f/(F_DLAT*F_RAD*cl);
  const int xp = (x==NX-1)?0:x+1, xm = (x==0)?NX-1:x-1;
  const float4 uxp = *(const float4*)&u[i4(b,y,xp,zq*4)];
  const float4 uxm = *(const float4*)&u[i4(b,y,xm,zq*4)];
  float4 vyp, vym; float cy;
  if (y == 0)          { vyp = *(const float4*)&v[i4(b,1,x,zq*4)];    vym = *(const float4*)&v[i4(b,0,x,zq*4)];    cy = 1.0f/F_DYR; }
  else if (y == NY-1)  { vyp = *(const float4*)&v[i4(b,NY-1,x,zq*4)]; vym = *(const float4*)&v[i4(b,NY-2,x,zq*4)]; cy = 1.0f/F_DYR; }
  else                 { vyp = *(const float4*)&v[i4(b,y+1,x,zq*4)];  vym = *(const float4*)&v[i4(b,y-1,x,zq*4)];  cy = 0.5f/F_DYR; }
  float4 o;
  o.x = (uxp.x - uxm.x)*invdx + (vyp.x - vym.x)*cy;
  o.y = (uxp.y - uxm.y)*invdx + (vyp.y - vym.y)*cy;
  o.z = (uxp.z - uxm.z)*invdx + (vyp.z - vym.z)*cy;
  o.w = (uxp.w - uxm.w)*invdx + (vyp.w - vym.w)*cy;
  *(float4*)&divh[idx*4] = o;
}

// -------------------- kernel 2: tendencies, float4 over z (R15) ----------
__global__ __launch_bounds__(256) void k_tend(
    const float* __restrict__ u, const float* __restrict__ v,
    const float* __restrict__ T, const float* __restrict__ ps,
    const float* __restrict__ Rp, const float* __restrict__ divh,
    float* __restrict__ du, float* __restrict__ dv,
    float* __restrict__ dT, float* __restrict__ dps) {
  const int tid = threadIdx.x;
  const int zl  = tid & 7;
  const int bswz = (blockIdx.x & 7) * 2025 + (blockIdx.x >> 3);
  const int col = bswz*32 + (tid>>3);              // 16200*32 = NCOL
  const int x = col % NX;
  const int y = (col / NX) % NY;
  const int b = col / (NX*NY);
  const float R = Rp[0];

  const int xp = (x==NX-1)?0:x+1, xm = (x==0)?NX-1:x-1;
  const int ycm = (y>0)? y-1 : 0;
  const int ycp = (y<NY-1)? y+1 : NY-1;
  const bool y0 = (y==0), yN = (y==NY-1);

  const float lat  = -F_HPI + (y+0.5f)*F_DLAT;
  const float cl   = cosf(lat);
  const float fcor = 2.0f*F_OMEGA*sinf(lat);
  const float sx     = F_DLAT*F_RAD*cl;
  const float invdx  = 0.5f/sx;
  const float inv2dy = 0.5f/F_DYR;
  const float inv1dy = 1.0f/F_DYR;
  const float invsx2 = 1.0f/(sx*sx);
  const float invsy2 = 1.0f/(F_DYR*F_DYR);
  const float dsv = 1.0f/32.0f;
  const int zb = zl*4;
  float bk[4];
  #pragma unroll
  for (int j=0;j<4;++j) bk[j] = (zb + j + 0.5f)/32.0f;

  const int ic  = i4(b,y,x,zb),   ixp = i4(b,y,xp,zb), ixm = i4(b,y,xm,zb);
  const int iyp = i4(b,ycp,x,zb), iym = i4(b,ycm,x,zb);

  const float psc=ps[i3(b,y,x)],   psxp=ps[i3(b,y,xp)], psxm=ps[i3(b,y,xm)];
  const float psyp=ps[i3(b,ycp,x)], psym=ps[i3(b,ycm,x)];

  auto dfy1 = [&](float fc_, float fyp_, float fym_) -> float {
    if (y0) return (fyp_ - fc_) * inv1dy;
    if (yN) return (fc_ - fym_) * inv1dy;
    return (fyp_ - fym_) * inv2dy;
  };
  auto lap1 = [&](float fc_, float fxp_, float fxm_, float fyp_, float fym_) -> float {
    float d2x = (fxp_ + fxm_ - 2.0f*fc_) * invsx2;
    float d2y = (y0||yN) ? 0.0f : (fyp_ + fym_ - 2.0f*fc_) * invsy2;
    return d2x + d2y;
  };
  auto suf32 = [&](const float vv[4], float out[4]) {
    const float s3 = vv[3], s2 = vv[2]+s3, s1 = vv[1]+s2, s0 = vv[0]+s1;
    float S = s0;
    { float t=__shfl_down(S,1,8); if (zl+1<8) S+=t; }
    { float t=__shfl_down(S,2,8); if (zl+2<8) S+=t; }
    { float t=__shfl_down(S,4,8); if (zl+4<8) S+=t; }
    const float hi = S - s0;
    out[0]=s0+hi; out[1]=s1+hi; out[2]=s2+hi; out[3]=s3+hi;
  };
  auto pre32 = [&](const float vv[4], float out[4], float& tot) {
    const float p0 = vv[0], p1 = vv[1]+p0, p2 = vv[2]+p1, p3 = vv[3]+p2;
    float P = p3;
    { float t=__shfl_up(P,1,8); if (zl>=1) P+=t; }
    { float t=__shfl_up(P,2,8); if (zl>=2) P+=t; }
    { float t=__shfl_up(P,4,8); if (zl>=4) P+=t; }
    const float lo = P - p3;
    out[0]=p0+lo; out[1]=p1+lo; out[2]=p2+lo; out[3]=p3+lo;
    tot = __shfl(P, 7, 8);
  };
  auto vg4 = [&](const float c[4], float out[4]) {
    const float up = __shfl_up(c[3], 1, 8);    // z-1 for j=0
    const float dn = __shfl_down(c[0], 1, 8);  // z+1 for j=3
    out[0] = (zl==0) ? (c[1]-c[0])*32.0f : (c[1]-up)*16.0f;
    out[1] = (c[2]-c[0])*16.0f;
    out[2] = (c[3]-c[1])*16.0f;
    out[3] = (zl==7) ? (c[3]-c[2])*32.0f : (dn-c[2])*16.0f;
  };
  auto unpack = [](const float4 f, float a[4]) { a[0]=f.x; a[1]=f.y; a[2]=f.z; a[3]=f.w; };

  float ucv[4], dudx[4], dudy[4], lapu[4], vgu[4];
  {
    float c[4],a[4],m[4],p[4],q[4];
    unpack(*(const float4*)&u[ic],c);  unpack(*(const float4*)&u[ixp],a);
    unpack(*(const float4*)&u[ixm],m); unpack(*(const float4*)&u[iyp],p);
    unpack(*(const float4*)&u[iym],q);
    #pragma unroll
    for (int j=0;j<4;++j){ ucv[j]=c[j]; dudx[j]=(a[j]-m[j])*invdx;
      dudy[j]=dfy1(c[j],p[j],q[j]); lapu[j]=lap1(c[j],a[j],m[j],p[j],q[j]); }
    vg4(ucv, vgu);
  }
  float vcv[4], dvdx[4], dvdy[4], lapv[4], vgv[4];
  {
    float c[4],a[4],m[4],p[4],q[4];
    unpack(*(const float4*)&v[ic],c);  unpack(*(const float4*)&v[ixp],a);
    unpack(*(const float4*)&v[ixm],m); unpack(*(const float4*)&v[iyp],p);
    unpack(*(const float4*)&v[iym],q);
    #pragma unroll
    for (int j=0;j<4;++j){ vcv[j]=c[j]; dvdx[j]=(a[j]-m[j])*invdx;
      dvdy[j]=dfy1(c[j],p[j],q[j]); lapv[j]=lap1(c[j],a[j],m[j],p[j],q[j]); }
    vg4(vcv, vgv);
  }
  float Tcv[4], dTdx[4], dTdy[4], lapT[4], vgT[4];
  {
    float c[4],a[4],m[4],p[4],q[4];
    unpack(*(const float4*)&T[ic],c);  unpack(*(const float4*)&T[ixp],a);
    unpack(*(const float4*)&T[ixm],m); unpack(*(const float4*)&T[iyp],p);
    unpack(*(const float4*)&T[iym],q);
    #pragma unroll
    for (int j=0;j<4;++j){ Tcv[j]=c[j]; dTdx[j]=(a[j]-m[j])*invdx;
      dTdy[j]=dfy1(c[j],p[j],q[j]); lapT[j]=lap1(c[j],a[j],m[j],p[j],q[j]); }
    vg4(Tcv, vgT);
  }
  float Dcv[4], gdivx[4], gdivy[4];
  {
    float c[4],a[4],m[4],p[4],q[4];
    unpack(*(const float4*)&divh[ic],c);  unpack(*(const float4*)&divh[ixp],a);
    unpack(*(const float4*)&divh[ixm],m); unpack(*(const float4*)&divh[iyp],p);
    unpack(*(const float4*)&divh[iym],q);
    #pragma unroll
    for (int j=0;j<4;++j){ Dcv[j]=c[j]; gdivx[j]=(a[j]-m[j])*invdx;
      gdivy[j]=dfy1(c[j],p[j],q[j]); }
  }

  const float dpsdx = (psxp-psxm)*invdx;
  const float dpsdy = dfy1(psc,psyp,psym);

  float dphidx[4], dphidy[4];
  {
    float a[4], bvv[4];
    #pragma unroll
    for (int j=0;j<4;++j){ const float rz = R*dsv/bk[j]; a[j]=rz*dTdx[j]; bvv[j]=rz*dTdy[j]; }
    suf32(a, dphidx);
    suf32(bvv, dphidy);
  }

  float mass[4], Ipre[4], tot;
  #pragma unroll
  for (int j=0;j<4;++j) mass[j] = Dcv[j]*psc + ucv[j]*dpsdx + vcv[j]*dpsdy;
  pre32(mass, Ipre, tot);
  const float Itot = tot * dsv;
  float sigd[4];
  #pragma unroll
  for (int j=0;j<4;++j) sigd[j] = (bk[j]*Itot - Ipre[j]*dsv) / (psc + 1e-8f);

  const float cf2  = fmaxf(cl*cl, 0.01f);
  const float nudiv = 500000.0f*cf2, nuh = 100000.0f*cf2;

  float outu[4], outv[4], outT[4];
  #pragma unroll
  for (int j=0;j<4;++j){
    const float pfac = R*Tcv[j]*bk[j]/(bk[j]*psc + 1e-8f);
    const float pgfu = -dphidx[j] - pfac*dpsdx;
    const float pgfv = -dphidy[j] - pfac*dpsdy;
    const float adiab = R*Tcv[j]/(bk[j]*psc*F_CP + 1e-8f) * (sigd[j]*psc);
    outu[j] = -(ucv[j]*dudx[j] + vcv[j]*dudy[j]) - sigd[j]*vgu[j] + fcor*vcv[j] + pgfu
              + nuh*lapu[j] - 1e-5f*ucv[j] + nudiv*gdivx[j];
    outv[j] = -(ucv[j]*dvdx[j] + vcv[j]*dvdy[j]) - sigd[j]*vgv[j] - fcor*ucv[j] + pgfv
              + nuh*lapv[j] - 1e-5f*vcv[j] + nudiv*gdivy[j];
    outT[j] = -(ucv[j]*dTdx[j] + vcv[j]*dTdy[j]) - sigd[j]*vgT[j] + adiab + nuh*lapT[j];
  }
  *(float4*)&du[ic] = make_float4(outu[0],outu[1],outu[2],outu[3]);
  *(float4*)&dv[ic] = make_float4(outv[0],outv[1],outv[2],outv[3]);
  *(float4*)&dT[ic] = make_float4(outT[0],outT[1],outT[2],outT[3]);
  if (zl == 0) dps[col] = -Itot;
}

// -------------------- polar filter helpers --------------------
__device__ __forceinline__ void filter_band(int y, int& k0, int& k1, bool& keepmode) {
  float lat = -F_HPI + (y+0.5f)*F_DLAT;
  float cut = fmaxf(360.0f*cosf(lat), 1.0f);
  int M = (int)floorf(cut);
  keepmode = (M <= 179);
  k0 = keepmode ? 0 : (M+1);
  k1 = keepmode ? M : 360;
}

// -------------------- kernel 3: folded-DFT polar filter ------------------
// R16 base + synthesis k-SPLIT: 364 threads = (kh 0/1 adjacent lanes, p, zh);
// lane kh takes k = kst+4*kh step 8 (rotation step 8p*theta). Total FMAs &
// rotations invariant (each k visited once — unlike R15's z-split); chains
// halve, active synthesis waves 3 -> 6. All lx/lm accumulators are linear
// in the partials -> one shfl_xor(1) combine is exact. Epilogue splits:
// kh=0 writes x=p, kh=1 writes mirror.
#define FKMAX 180
__global__ __launch_bounds__(384, 4) void k_filter4b(
    float* __restrict__ du, float* __restrict__ dv, float* __restrict__ dT,
    float* __restrict__ dps, float* __restrict__ dq) {
  __shared__ __align__(16) float smem[8704];   // 34.816 KB

  const int tid = threadIdx.x;
  const int xcd = blockIdx.x & 7;
  const int s   = blockIdx.x >> 3;                 // 0..1171
  const int bid = ((s >> 2) * 8 + xcd) * 4 + (s & 3);
  if (bid >= 9360) return;

  if (bid >= 8640) {
    // ---------------- dpsdt filter path (720 blocks) ----------------
    float*  f  = smem;                          // [720]
    float2* tw = (float2*)(smem + 720);         // [720]
    float*  sc = smem + 720 + 1440;             // [184]
    float*  ss = sc + 184;
    const int row = bid - 8640;                 // 0..719 = b*360+y
    const int y = row % NY;
    float* base = dps + (size_t)row*NX;
    for (int t = tid; t < NX; t += 384) {
      float a = (float)t * TH;
      float sv, cv; sincosf(a, &sv, &cv);
      tw[t] = make_float2(cv, sv);
      f[t] = base[t];
    }
    int k0, k1; bool keepmode;
    filter_band(y, k0, k1, keepmode);
    const int nk = k1 - k0 + 1;
    __syncthreads();
    if (tid < nk) {
      const int k = k0 + tid;
      float ac=0.f, as=0.f; int idx=0;
      for (int xx=0; xx<NX; ++xx) {
        const float fv = f[xx];
        const float2 t2 = tw[idx];
        ac = fmaf(fv, t2.x, ac); as = fmaf(fv, t2.y, as);
        idx += k; if (idx >= NX) idx -= NX;
      }
      sc[tid]=ac; ss[tid]=as;
    }
    __syncthreads();
    if (tid < 360) {
      const int x0 = tid, x1 = tid + 360;
      const int t0 = (x0 * k0) % NX;
      const int t1 = (x1 * k0) % NX;
      float c0 = tw[t0].x, s0 = tw[t0].y;
      float c1 = tw[t1].x, s1 = tw[t1].y;
      const float dc0 = tw[x0].x, dn0 = tw[x0].y;
      const float dc1 = tw[x1].x, dn1 = tw[x1].y;
      float a0 = 0.f, a1 = 0.f;
      for (int kk = 0; kk < nk; ++kk) {
        const int k = k0 + kk;
        const float w = (k==0 || k==360) ? 1.0f : 2.0f;
        a0 = fmaf(sc[kk], w*c0, fmaf(ss[kk], w*s0, a0));
        a1 = fmaf(sc[kk], w*c1, fmaf(ss[kk], w*s1, a1));
        float n0 = c0*dc0 - s0*dn0; s0 = c0*dn0 + s0*dc0; c0 = n0;
        float n1 = c1*dc1 - s1*dn1; s1 = c1*dn1 + s1*dc1; c1 = n1;
      }
      const float inv = 1.0f/720.0f;
      float o0 = keepmode ? a0*inv : f[x0] - a0*inv;
      float o1 = keepmode ? a1*inv : f[x1] - a1*inv;
      o0 = fminf(fmaxf(o0, -0.5f), 0.5f);
      o1 = fminf(fmaxf(o1, -0.5f), 0.5f);
      base[x0] = o0;
      base[x1] = o1;
    }
    return;
  }

  // ---------------- field filter path (8640 blocks) ----------------
  float* S0p = smem + 0;       // [91][8]
  float* S0m = smem + 728;
  float* S2p = smem + 1456;
  float* S2m = smem + 2184;
  float* Q1a = smem + 2912;
  float* Q2a = smem + 3640;
  float* Q3a = smem + 4368;
  float* Q4a = smem + 5096;
  float (*SD)[8][2] = (float(*)[8][2])(smem + 5824);  // [180][8][2]

  // fused k_zero: each field block zeroes its 1920-float dq slice
  {
    float4* dqv = (float4*)dq + (size_t)bid * 480;
    const float4 z4 = make_float4(0.f,0.f,0.f,0.f);
    for (int t = tid; t < 480; t += 384) dqv[t] = z4;
  }

  const int zq   = bid & 3;
  const int rest = bid >> 2;
  const int by   = rest % (NB*NY);
  const int fld  = rest / (NB*NY);
  const int y = by % NY, b = by / NY;
  float* fptr = (fld==0)? du : (fld==1)? dv : dT;
  const float clipv = (fld==2)? 0.01f : 0.02f;
  float* base = fptr + ((size_t)(b*NY+y)*NX)*NZ + zq*8;

  int k0, k1; bool keep;
  filter_band(y, k0, k1, keep);

  // ---- load + fold4 + mirror-fold (tid<182: pair-slot p, z-half zh) ----
  if (tid < 182) {
    const int p  = tid % 91;
    const int zh = tid / 91;
    const bool hasm = (p >= 1 && p <= 89);
    const int xm = 180 - p;
    const float4 q0 = *(const float4*)(base + (size_t)(p      )*NZ + zh*4);
    const float4 q1 = *(const float4*)(base + (size_t)(p + 180)*NZ + zh*4);
    const float4 q2 = *(const float4*)(base + (size_t)(p + 360)*NZ + zh*4);
    const float4 q3 = *(const float4*)(base + (size_t)(p + 540)*NZ + zh*4);
    float4 m0 = make_float4(0,0,0,0), m1 = m0, m2 = m0, m3 = m0;
    if (hasm) {
      m0 = *(const float4*)(base + (size_t)(xm      )*NZ + zh*4);
      m1 = *(const float4*)(base + (size_t)(xm + 180)*NZ + zh*4);
      m2 = *(const float4*)(base + (size_t)(xm + 360)*NZ + zh*4);
      m3 = *(const float4*)(base + (size_t)(xm + 540)*NZ + zh*4);
    }
    const int o = p*8 + zh*4;
    #pragma unroll
    for (int j = 0; j < 4; ++j) {
      const float a0 = (j==0)?q0.x:(j==1)?q0.y:(j==2)?q0.z:q0.w;
      const float a1 = (j==0)?q1.x:(j==1)?q1.y:(j==2)?q1.z:q1.w;
      const float a2 = (j==0)?q2.x:(j==1)?q2.y:(j==2)?q2.z:q2.w;
      const float a3 = (j==0)?q3.x:(j==1)?q3.y:(j==2)?q3.z:q3.w;
      const float b0 = (j==0)?m0.x:(j==1)?m0.y:(j==2)?m0.z:m0.w;
      const float b1 = (j==0)?m1.x:(j==1)?m1.y:(j==2)?m1.z:m1.w;
      const float b2 = (j==0)?m2.x:(j==1)?m2.y:(j==2)?m2.z:m2.w;
      const float b3 = (j==0)?m3.x:(j==1)?m3.y:(j==2)?m3.z:m3.w;
      const float s0  = a0+a1+a2+a3, s2  = a0-a1+a2-a3, A  = a0-a2, B  = a1-a3;
      const float s0M = b0+b1+b2+b3, s2M = b0-b1+b2-b3, AM = b0-b2, BM = b1-b3;
      S0p[o+j] = s0 + s0M;  S0m[o+j] = s0 - s0M;
      S2p[o+j] = s2 + s2M;  S2m[o+j] = s2 - s2M;
      Q1a[o+j] = A - BM;    Q2a[o+j] = AM - B;
      Q3a[o+j] = AM + B;    Q4a[o+j] = A + BM;
    }
  }
  __syncthreads();

  // ---- analysis: thread = (ks 0..95, xq 0..3); one k, 8 z, 91 slots ----
  {
    const int xq = tid & 3;
    const int ks = tid >> 2;            // 0..95; waves 0-2 even-class, 3-5 odd
    const bool isodd = (ks >= 48);
    const int slot = isodd ? ks - 48 : ks;
    const int ke0 = k0 + (k0 & 1);      // first even >= k0
    const int ko0 = k0 | 1;             // first odd  >= k0
    const int kbase = isodd ? ko0 : ke0;
    const int cnt   = (k1 >= kbase) ? (((k1 - kbase) >> 1) + 1) : 0;
    const bool dual = (cnt > 48);
    int k, x0, xe; bool act;
    if (dual) { k = kbase + 2*(slot + 48*(xq>>1)); x0 = (xq&1)?46:0; xe = (xq&1)?91:46; act = (k <= k1); }
    else      { k = kbase + 2*slot; x0 = 23*xq; xe = (xq==3)?91:(x0+23); act = (slot < cnt); }

    float ac[8], as[8];
    #pragma unroll
    for (int j=0;j<8;++j){ ac[j]=0.f; as[j]=0.f; }

    if (act) {
      float dc, ds; sincosf((float)k * TH, &ds, &dc);
      float c, s;   sincosf((float)((k * x0) % 720) * TH, &s, &c);
      const int n = xe - x0;
      if (!isodd) {
        const int r = k & 3;
        const float* Pc = ((r == 0) ? S0p : S2m) + x0*8;
        const float* Ps = ((r == 0) ? S0m : S2p) + x0*8;
        #pragma unroll 4
        for (int i = 0; i < n; ++i) {
          const float4 c0 = *(const float4*)(Pc + i*8);
          const float4 c1 = *(const float4*)(Pc + i*8 + 4);
          const float4 s0v = *(const float4*)(Ps + i*8);
          const float4 s1v = *(const float4*)(Ps + i*8 + 4);
          ac[0]=fmaf(c0.x ,c,ac[0]); as[0]=fmaf(s0v.x,s,as[0]);
          ac[1]=fmaf(c0.y ,c,ac[1]); as[1]=fmaf(s0v.y,s,as[1]);
          ac[2]=fmaf(c0.z ,c,ac[2]); as[2]=fmaf(s0v.z,s,as[2]);
          ac[3]=fmaf(c0.w ,c,ac[3]); as[3]=fmaf(s0v.w,s,as[3]);
          ac[4]=fmaf(c1.x ,c,ac[4]); as[4]=fmaf(s1v.x,s,as[4]);
          ac[5]=fmaf(c1.y ,c,ac[5]); as[5]=fmaf(s1v.y,s,as[5]);
          ac[6]=fmaf(c1.z ,c,ac[6]); as[6]=fmaf(s1v.z,s,as[6]);
          ac[7]=fmaf(c1.w ,c,ac[7]); as[7]=fmaf(s1v.w,s,as[7]);
          const float nc = fmaf(c, dc, -s*ds);
          s = fmaf(s, dc, c*ds); c = nc;
        }
      } else {
        const float sg = ((k & 3) == 1) ? 1.0f : -1.0f;
        const float* p1 = Q1a + x0*8; const float* p2 = Q2a + x0*8;
        const float* p3 = Q3a + x0*8; const float* p4 = Q4a + x0*8;
        #pragma unroll 2
        for (int i = 0; i < n; ++i) {
          const float4 u10 = *(const float4*)(p1 + i*8);
          const float4 u11 = *(const float4*)(p1 + i*8 + 4);
          const float4 u20 = *(const float4*)(p2 + i*8);
          const float4 u21 = *(const float4*)(p2 + i*8 + 4);
          const float4 u30 = *(const float4*)(p3 + i*8);
          const float4 u31 = *(const float4*)(p3 + i*8 + 4);
          const float4 u40 = *(const float4*)(p4 + i*8);
          const float4 u41 = *(const float4*)(p4 + i*8 + 4);
          const float svs = sg*s, cvs = sg*c;
          ac[0]=fmaf(u10.x,c,fmaf(u20.x,svs,ac[0])); as[0]=fmaf(u30.x,cvs,fmaf(u40.x,s,as[0]));
          ac[1]=fmaf(u10.y,c,fmaf(u20.y,svs,ac[1])); as[1]=fmaf(u30.y,cvs,fmaf(u40.y,s,as[1]));
          ac[2]=fmaf(u10.z,c,fmaf(u20.z,svs,ac[2])); as[2]=fmaf(u30.z,cvs,fmaf(u40.z,s,as[2]));
          ac[3]=fmaf(u10.w,c,fmaf(u20.w,svs,ac[3])); as[3]=fmaf(u30.w,cvs,fmaf(u40.w,s,as[3]));
          ac[4]=fmaf(u11.x,c,fmaf(u21.x,svs,ac[4])); as[4]=fmaf(u31.x,cvs,fmaf(u41.x,s,as[4]));
          ac[5]=fmaf(u11.y,c,fmaf(u21.y,svs,ac[5])); as[5]=fmaf(u31.y,cvs,fmaf(u41.y,s,as[5]));
          ac[6]=fmaf(u11.z,c,fmaf(u21.z,svs,ac[6])); as[6]=fmaf(u31.z,cvs,fmaf(u41.z,s,as[6]));
          ac[7]=fmaf(u11.w,c,fmaf(u21.w,svs,ac[7])); as[7]=fmaf(u31.w,cvs,fmaf(u41.w,s,as[7]));
          const float nc = fmaf(c, dc, -s*ds);
          s = fmaf(s, dc, c*ds); c = nc;
        }
      }
    }
    // combine partial sums over the 4-lane xq group
    #pragma unroll
    for (int j=0;j<8;++j){
      ac[j] += __shfl_xor(ac[j], 1);
      as[j] += __shfl_xor(as[j], 1);
    }
    if (!dual) {
      #pragma unroll
      for (int j=0;j<8;++j){
        ac[j] += __shfl_xor(ac[j], 2);
        as[j] += __shfl_xor(as[j], 2);
      }
    }
    if (act && ((xq & (dual ? 1 : 3)) == 0)) {
      const float w = (k==0 || k==360) ? 1.0f : 2.0f;
      const int r = k - k0;
      *(float4*)&SD[r][0][0] = make_float4(w*ac[0], w*as[0], w*ac[1], w*as[1]);
      *(float4*)&SD[r][2][0] = make_float4(w*ac[2], w*as[2], w*ac[3], w*as[3]);
      *(float4*)&SD[r][4][0] = make_float4(w*ac[4], w*as[4], w*ac[5], w*as[5]);
      *(float4*)&SD[r][6][0] = make_float4(w*ac[6], w*as[6], w*ac[7], w*as[7]);
    }
  }
  __syncthreads();

  // ---- synthesis: thread = (kh, pair p, zh); lane kh covers k=kst+4*kh step 8 ----
  if (tid < 364) {
    const int kh = tid & 1;
    const int pz = tid >> 1;          // 0..181
    const int p  = pz % 91;
    const int zh = pz / 91;
    const bool hasm = (p >= 1 && p <= 89);
    float lx0[4],lx1[4],lx2[4],lx3[4], lm0[4],lm1[4],lm2[4],lm3[4];
    #pragma unroll
    for (int j=0;j<4;++j){ lx0[j]=lx1[j]=lx2[j]=lx3[j]=0.f; lm0[j]=lm1[j]=lm2[j]=lm3[j]=0.f; }

    const int m8 = (8*p) % 720;
    float dstep_s, dstep_c; sincosf((float)m8 * TH, &dstep_s, &dstep_c);

    // even residues r=0,2: split cos/sin sums P,S
    #pragma unroll
    for (int ri = 0; ri < 2; ++ri) {
      const int r = ri*2;
      const float tau = (ri==0)? 1.0f : -1.0f;
      const int kst = k0 + ((r - (k0 & 3) + 4) & 3) + 4*kh;
      if (kst > k1) continue;
      float P[4]={0,0,0,0}, S[4]={0,0,0,0};
      float sv, cv; sincosf((float)(((long)kst * p) % 720) * TH, &sv, &cv);
      #pragma unroll 2
      for (int k = kst; k <= k1; k += 8) {
        const float4 d01 = *(const float4*)&SD[k - k0][zh*4 + 0][0];
        const float4 d23 = *(const float4*)&SD[k - k0][zh*4 + 2][0];
        P[0]=fmaf(d01.x,cv,P[0]); S[0]=fmaf(d01.y,sv,S[0]);
        P[1]=fmaf(d01.z,cv,P[1]); S[1]=fmaf(d01.w,sv,S[1]);
        P[2]=fmaf(d23.x,cv,P[2]); S[2]=fmaf(d23.y,sv,S[2]);
        P[3]=fmaf(d23.z,cv,P[3]); S[3]=fmaf(d23.w,sv,S[3]);
        float nc = fmaf(cv, dstep_c, -sv*dstep_s);   // forward +8p*theta
        float ns = fmaf(sv, dstep_c,  cv*dstep_s);
        cv = nc; sv = ns;
      }
      #pragma unroll
      for (int j=0;j<4;++j){
        const float hx = P[j] + S[j];
        const float hm = (ri==0) ? (P[j] - S[j]) : (S[j] - P[j]);
        lx0[j]+=hx; lx2[j]+=hx; lx1[j]+=tau*hx; lx3[j]+=tau*hx;
        lm0[j]+=hm; lm2[j]+=hm; lm1[j]+=tau*hm; lm3[j]+=tau*hm;
      }
    }
    // odd residues r=1,3: 4 split sums Cc,Cs,Sc,Ss
    #pragma unroll
    for (int ri = 0; ri < 2; ++ri) {
      const int r = ri*2 + 1;
      const float sig = (ri==0)? 1.0f : -1.0f;
      const int kst = k0 + ((r - (k0 & 3) + 4) & 3) + 4*kh;
      if (kst > k1) continue;
      float Cc[4]={0,0,0,0}, Cs[4]={0,0,0,0}, Sc[4]={0,0,0,0}, Ss[4]={0,0,0,0};
      float sv, cv; sincosf((float)(((long)kst * p) % 720) * TH, &sv, &cv);
      #pragma unroll 2
      for (int k = kst; k <= k1; k += 8) {
        const float4 d01 = *(const float4*)&SD[k - k0][zh*4 + 0][0];
        const float4 d23 = *(const float4*)&SD[k - k0][zh*4 + 2][0];
        Cc[0]=fmaf(d01.x,cv,Cc[0]); Cs[0]=fmaf(d01.x,sv,Cs[0]);
        Sc[0]=fmaf(d01.y,cv,Sc[0]); Ss[0]=fmaf(d01.y,sv,Ss[0]);
        Cc[1]=fmaf(d01.z,cv,Cc[1]); Cs[1]=fmaf(d01.z,sv,Cs[1]);
        Sc[1]=fmaf(d01.w,cv,Sc[1]); Ss[1]=fmaf(d01.w,sv,Ss[1]);
        Cc[2]=fmaf(d23.x,cv,Cc[2]); Cs[2]=fmaf(d23.x,sv,Cs[2]);
        Sc[2]=fmaf(d23.y,cv,Sc[2]); Ss[2]=fmaf(d23.y,sv,Ss[2]);
        Cc[3]=fmaf(d23.z,cv,Cc[3]); Cs[3]=fmaf(d23.z,sv,Cs[3]);
        Sc[3]=fmaf(d23.w,cv,Sc[3]); Ss[3]=fmaf(d23.w,sv,Ss[3]);
        float nc = fmaf(cv, dstep_c, -sv*dstep_s);
        float ns = fmaf(sv, dstep_c,  cv*dstep_s);
        cv = nc; sv = ns;
      }
      #pragma unroll
      for (int j=0;j<4;++j){
        const float hrx = Cc[j] + Ss[j];
        const float hix = Sc[j] - Cs[j];
        const float hrm = sig*(Cs[j] + Sc[j]);
        const float him = Ss[j] - Cc[j];
        lx0[j]+=hrx; lx2[j]-=hrx; lx1[j]+=sig*hix; lx3[j]-=sig*hix;
        lm0[j]+=hrm; lm2[j]-=hrm; lm1[j]+=him;     lm3[j]-=him;
      }
    }

    // combine k-halves across adjacent lane pairs (all accumulators linear)
    #pragma unroll
    for (int j=0;j<4;++j){
      lx0[j] += __shfl_xor(lx0[j], 1); lx1[j] += __shfl_xor(lx1[j], 1);
      lx2[j] += __shfl_xor(lx2[j], 1); lx3[j] += __shfl_xor(lx3[j], 1);
      lm0[j] += __shfl_xor(lm0[j], 1); lm1[j] += __shfl_xor(lm1[j], 1);
      lm2[j] += __shfl_xor(lm2[j], 1); lm3[j] += __shfl_xor(lm3[j], 1);
    }

    const float inv = 1.0f/720.0f;
    if (kh == 0) {
      // x = p outputs
      float qx[4][4];
      if (!keep) {
        const int o = p*8 + zh*4;
        #pragma unroll
        for (int j=0;j<4;++j){
          const float s0x = 0.5f*(S0p[o+j] + S0m[o+j]);
          const float s2x = 0.5f*(S2p[o+j] + S2m[o+j]);
          const float Ax  = 0.5f*(Q1a[o+j] + Q4a[o+j]);
          const float Bx  = 0.5f*(Q3a[o+j] - Q2a[o+j]);
          const float sp = 0.25f*(s0x + s2x), sm = 0.25f*(s0x - s2x);
          qx[0][j] = sp + 0.5f*Ax; qx[1][j] = sm + 0.5f*Bx;
          qx[2][j] = sp - 0.5f*Ax; qx[3][j] = sm - 0.5f*Bx;
        }
      }
      float o[4][4];
      #pragma unroll
      for (int j=0;j<4;++j){
        float l0 = lx0[j]*inv, l1 = lx1[j]*inv, l2 = lx2[j]*inv, l3 = lx3[j]*inv;
        if (!keep) { l0 = qx[0][j]-l0; l1 = qx[1][j]-l1; l2 = qx[2][j]-l2; l3 = qx[3][j]-l3; }
        o[0][j] = fminf(fmaxf(l0,-clipv),clipv);
        o[1][j] = fminf(fmaxf(l1,-clipv),clipv);
        o[2][j] = fminf(fmaxf(l2,-clipv),clipv);
        o[3][j] = fminf(fmaxf(l3,-clipv),clipv);
      }
      #pragma unroll
      for (int jj=0;jj<4;++jj)
        *(float4*)(base + (size_t)(p + 180*jj)*NZ + zh*4) =
            make_float4(o[jj][0], o[jj][1], o[jj][2], o[jj][3]);
    } else if (hasm) {
      // mirror x = 180-p outputs
      const int xm = 180 - p;
      float qm[4][4];
      if (!keep) {
        const int o = p*8 + zh*4;
        #pragma unroll
        for (int j=0;j<4;++j){
          const float s0M = 0.5f*(S0p[o+j] - S0m[o+j]);
          const float s2M = 0.5f*(S2p[o+j] - S2m[o+j]);
          const float AM  = 0.5f*(Q2a[o+j] + Q3a[o+j]);
          const float BM  = 0.5f*(Q4a[o+j] - Q1a[o+j]);
          const float sp = 0.25f*(s0M + s2M), sm = 0.25f*(s0M - s2M);
          qm[0][j] = sp + 0.5f*AM; qm[1][j] = sm + 0.5f*BM;
          qm[2][j] = sp - 0.5f*AM; qm[3][j] = sm - 0.5f*BM;
        }
      }
      float o[4][4];
      #pragma unroll
      for (int j=0;j<4;++j){
        float l0 = lm0[j]*inv, l1 = lm1[j]*inv, l2 = lm2[j]*inv, l3 = lm3[j]*inv;
        if (!keep) { l0 = qm[0][j]-l0; l1 = qm[1][j]-l1; l2 = qm[2][j]-l2; l3 = qm[3][j]-l3; }
        o[0][j] = fminf(fmaxf(l0,-clipv),clipv);
        o[1][j] = fminf(fmaxf(l1,-clipv),clipv);
        o[2][j] = fminf(fmaxf(l2,-clipv),clipv);
        o[3][j] = fminf(fmaxf(l3,-clipv),clipv);
      }
      #pragma unroll
      for (int jj=0;jj<4;++jj)
        *(float4*)(base + (size_t)(xm + 180*jj)*NZ + zh*4) =
            make_float4(o[jj][0], o[jj][1], o[jj][2], o[jj][3]);
    }
  }
}

// -------------------- host --------------------
extern "C" void kernel_launch(void* const* d_in, const int* in_sizes, int n_in,
                              void* d_out, int out_size, void* d_ws, size_t ws_size,
                              hipStream_t stream) {
  (void)in_sizes; (void)n_in; (void)d_ws; (void)ws_size; (void)out_size;
  const float* u  = (const float*)d_in[0];
  const float* v  = (const float*)d_in[1];
  const float* T  = (const float*)d_in[2];
  const float* ps = (const float*)d_in[4];
  const float* Rp = (const float*)d_in[6];

  float* out = (float*)d_out;
  float* du  = out;
  float* dv  = out + (size_t)NPTS;
  float* dT  = out + (size_t)2*NPTS;
  float* dq  = out + (size_t)3*NPTS;   // staged as div_h scratch; zeroed in filter
  float* dps = out + (size_t)4*NPTS;

  k_divh<<<NPTS/(256*4), 256, 0, stream>>>(u, v, dq);
  k_tend<<<NCOL/32,      256, 0, stream>>>(u, v, T, ps, Rp, dq, du, dv, dT, dps);
  k_filter4b<<<9376, 384, 0, stream>>>(du, dv, dT, dps, dq);
}

// Round 18
// 421.515 us; speedup vs baseline: 1.1587x; 1.1587x over previous
//
#include <hip/hip_runtime.h>
#include <math.h>

#define NB 2
#define NY 360
#define NX 720
#define NZ 32
#define NPTS (NB*NY*NX*NZ)     // 16,588,800
#define NCOL (NB*NY*NX)        // 518,400

__device__ __forceinline__ int i4(int b,int y,int x,int z){ return (((b*NY)+y)*NX+x)*NZ+z; }
__device__ __forceinline__ int i3(int b,int y,int x){ return ((b*NY)+y)*NX+x; }

#define F_RAD   6371000.0f
#define F_OMEGA 7.292e-5f
#define F_CP    1004.0f
#define F_DLAT  ((float)(M_PI/360.0))                 /* == dlon */
#define F_DYR   ((float)(M_PI/360.0*6371000.0))      /* dlat*RAD */
#define F_HPI   ((float)(M_PI/2.0))
#define TH      ((float)(2.0*M_PI/720.0))

// -------------------- kernel 1: div_h (float4 over z, R14) --------------
__global__ __launch_bounds__(256) void k_divh(const float* __restrict__ u,
                                              const float* __restrict__ v,
                                              float* __restrict__ divh) {
  const int bswz = (blockIdx.x & 7) * 2025 + (blockIdx.x >> 3);
  const int idx = bswz*256 + threadIdx.x;          // quad index: NPTS/4 total
  const int zq = idx & 7;
  const int x  = (idx >> 3) % NX;
  const int by = idx / (NX*8);
  const int y  = by % NY;
  const int b  = by / NY;
  const float lat = -F_HPI + (y+0.5f)*F_DLAT;
  const float cl  = cosf(lat);
  const float invdx = 0.5f/(F_DLAT*F_RAD*cl);
  const int xp = (x==NX-1)?0:x+1, xm = (x==0)?NX-1:x-1;
  const float4 uxp = *(const float4*)&u[i4(b,y,xp,zq*4)];
  const float4 uxm = *(const float4*)&u[i4(b,y,xm,zq*4)];
  float4 vyp, vym; float cy;
  if (y == 0)          { vyp = *(const float4*)&v[i4(b,1,x,zq*4)];    vym = *(const float4*)&v[i4(b,0,x,zq*4)];    cy = 1.0f/F_DYR; }
  else if (y == NY-1)  { vyp = *(const float4*)&v[i4(b,NY-1,x,zq*4)]; vym = *(const float4*)&v[i4(b,NY-2,x,zq*4)]; cy = 1.0f/F_DYR; }
  else                 { vyp = *(const float4*)&v[i4(b,y+1,x,zq*4)];  vym = *(const float4*)&v[i4(b,y-1,x,zq*4)];  cy = 0.5f/F_DYR; }
  float4 o;
  o.x = (uxp.x - uxm.x)*invdx + (vyp.x - vym.x)*cy;
  o.y = (uxp.y - uxm.y)*invdx + (vyp.y - vym.y)*cy;
  o.z = (uxp.z - uxm.z)*invdx + (vyp.z - vym.z)*cy;
  o.w = (uxp.w - uxm.w)*invdx + (vyp.w - vym.w)*cy;
  *(float4*)&divh[idx*4] = o;
}

// -------------------- kernel 2: tendencies, float4 over z (R15) ----------
__global__ __launch_bounds__(256) void k_tend(
    const float* __restrict__ u, const float* __restrict__ v,
    const float* __restrict__ T, const float* __restrict__ ps,
    const float* __restrict__ Rp, const float* __restrict__ divh,
    float* __restrict__ du, float* __restrict__ dv,
    float* __restrict__ dT, float* __restrict__ dps) {
  const int tid = threadIdx.x;
  const int zl  = tid & 7;
  const int bswz = (blockIdx.x & 7) * 2025 + (blockIdx.x >> 3);
  const int col = bswz*32 + (tid>>3);              // 16200*32 = NCOL
  const int x = col % NX;
  const int y = (col / NX) % NY;
  const int b = col / (NX*NY);
  const float R = Rp[0];

  const int xp = (x==NX-1)?0:x+1, xm = (x==0)?NX-1:x-1;
  const int ycm = (y>0)? y-1 : 0;
  const int ycp = (y<NY-1)? y+1 : NY-1;
  const bool y0 = (y==0), yN = (y==NY-1);

  const float lat  = -F_HPI + (y+0.5f)*F_DLAT;
  const float cl   = cosf(lat);
  const float fcor = 2.0f*F_OMEGA*sinf(lat);
  const float sx     = F_DLAT*F_RAD*cl;
  const float invdx  = 0.5f/sx;
  const float inv2dy = 0.5f/F_DYR;
  const float inv1dy = 1.0f/F_DYR;
  const float invsx2 = 1.0f/(sx*sx);
  const float invsy2 = 1.0f/(F_DYR*F_DYR);
  const float dsv = 1.0f/32.0f;
  const int zb = zl*4;
  float bk[4];
  #pragma unroll
  for (int j=0;j<4;++j) bk[j] = (zb + j + 0.5f)/32.0f;

  const int ic  = i4(b,y,x,zb),   ixp = i4(b,y,xp,zb), ixm = i4(b,y,xm,zb);
  const int iyp = i4(b,ycp,x,zb), iym = i4(b,ycm,x,zb);

  const float psc=ps[i3(b,y,x)],   psxp=ps[i3(b,y,xp)], psxm=ps[i3(b,y,xm)];
  const float psyp=ps[i3(b,ycp,x)], psym=ps[i3(b,ycm,x)];

  auto dfy1 = [&](float fc_, float fyp_, float fym_) -> float {
    if (y0) return (fyp_ - fc_) * inv1dy;
    if (yN) return (fc_ - fym_) * inv1dy;
    return (fyp_ - fym_) * inv2dy;
  };
  auto lap1 = [&](float fc_, float fxp_, float fxm_, float fyp_, float fym_) -> float {
    float d2x = (fxp_ + fxm_ - 2.0f*fc_) * invsx2;
    float d2y = (y0||yN) ? 0.0f : (fyp_ + fym_ - 2.0f*fc_) * invsy2;
    return d2x + d2y;
  };
  auto suf32 = [&](const float vv[4], float out[4]) {
    const float s3 = vv[3], s2 = vv[2]+s3, s1 = vv[1]+s2, s0 = vv[0]+s1;
    float S = s0;
    { float t=__shfl_down(S,1,8); if (zl+1<8) S+=t; }
    { float t=__shfl_down(S,2,8); if (zl+2<8) S+=t; }
    { float t=__shfl_down(S,4,8); if (zl+4<8) S+=t; }
    const float hi = S - s0;
    out[0]=s0+hi; out[1]=s1+hi; out[2]=s2+hi; out[3]=s3+hi;
  };
  auto pre32 = [&](const float vv[4], float out[4], float& tot) {
    const float p0 = vv[0], p1 = vv[1]+p0, p2 = vv[2]+p1, p3 = vv[3]+p2;
    float P = p3;
    { float t=__shfl_up(P,1,8); if (zl>=1) P+=t; }
    { float t=__shfl_up(P,2,8); if (zl>=2) P+=t; }
    { float t=__shfl_up(P,4,8); if (zl>=4) P+=t; }
    const float lo = P - p3;
    out[0]=p0+lo; out[1]=p1+lo; out[2]=p2+lo; out[3]=p3+lo;
    tot = __shfl(P, 7, 8);
  };
  auto vg4 = [&](const float c[4], float out[4]) {
    const float up = __shfl_up(c[3], 1, 8);    // z-1 for j=0
    const float dn = __shfl_down(c[0], 1, 8);  // z+1 for j=3
    out[0] = (zl==0) ? (c[1]-c[0])*32.0f : (c[1]-up)*16.0f;
    out[1] = (c[2]-c[0])*16.0f;
    out[2] = (c[3]-c[1])*16.0f;
    out[3] = (zl==7) ? (c[3]-c[2])*32.0f : (dn-c[2])*16.0f;
  };
  auto unpack = [](const float4 f, float a[4]) { a[0]=f.x; a[1]=f.y; a[2]=f.z; a[3]=f.w; };

  float ucv[4], dudx[4], dudy[4], lapu[4], vgu[4];
  {
    float c[4],a[4],m[4],p[4],q[4];
    unpack(*(const float4*)&u[ic],c);  unpack(*(const float4*)&u[ixp],a);
    unpack(*(const float4*)&u[ixm],m); unpack(*(const float4*)&u[iyp],p);
    unpack(*(const float4*)&u[iym],q);
    #pragma unroll
    for (int j=0;j<4;++j){ ucv[j]=c[j]; dudx[j]=(a[j]-m[j])*invdx;
      dudy[j]=dfy1(c[j],p[j],q[j]); lapu[j]=lap1(c[j],a[j],m[j],p[j],q[j]); }
    vg4(ucv, vgu);
  }
  float vcv[4], dvdx[4], dvdy[4], lapv[4], vgv[4];
  {
    float c[4],a[4],m[4],p[4],q[4];
    unpack(*(const float4*)&v[ic],c);  unpack(*(const float4*)&v[ixp],a);
    unpack(*(const float4*)&v[ixm],m); unpack(*(const float4*)&v[iyp],p);
    unpack(*(const float4*)&v[iym],q);
    #pragma unroll
    for (int j=0;j<4;++j){ vcv[j]=c[j]; dvdx[j]=(a[j]-m[j])*invdx;
      dvdy[j]=dfy1(c[j],p[j],q[j]); lapv[j]=lap1(c[j],a[j],m[j],p[j],q[j]); }
    vg4(vcv, vgv);
  }
  float Tcv[4], dTdx[4], dTdy[4], lapT[4], vgT[4];
  {
    float c[4],a[4],m[4],p[4],q[4];
    unpack(*(const float4*)&T[ic],c);  unpack(*(const float4*)&T[ixp],a);
    unpack(*(const float4*)&T[ixm],m); unpack(*(const float4*)&T[iyp],p);
    unpack(*(const float4*)&T[iym],q);
    #pragma unroll
    for (int j=0;j<4;++j){ Tcv[j]=c[j]; dTdx[j]=(a[j]-m[j])*invdx;
      dTdy[j]=dfy1(c[j],p[j],q[j]); lapT[j]=lap1(c[j],a[j],m[j],p[j],q[j]); }
    vg4(Tcv, vgT);
  }
  float Dcv[4], gdivx[4], gdivy[4];
  {
    float c[4],a[4],m[4],p[4],q[4];
    unpack(*(const float4*)&divh[ic],c);  unpack(*(const float4*)&divh[ixp],a);
    unpack(*(const float4*)&divh[ixm],m); unpack(*(const float4*)&divh[iyp],p);
    unpack(*(const float4*)&divh[iym],q);
    #pragma unroll
    for (int j=0;j<4;++j){ Dcv[j]=c[j]; gdivx[j]=(a[j]-m[j])*invdx;
      gdivy[j]=dfy1(c[j],p[j],q[j]); }
  }

  const float dpsdx = (psxp-psxm)*invdx;
  const float dpsdy = dfy1(psc,psyp,psym);

  float dphidx[4], dphidy[4];
  {
    float a[4], bvv[4];
    #pragma unroll
    for (int j=0;j<4;++j){ const float rz = R*dsv/bk[j]; a[j]=rz*dTdx[j]; bvv[j]=rz*dTdy[j]; }
    suf32(a, dphidx);
    suf32(bvv, dphidy);
  }

  float mass[4], Ipre[4], tot;
  #pragma unroll
  for (int j=0;j<4;++j) mass[j] = Dcv[j]*psc + ucv[j]*dpsdx + vcv[j]*dpsdy;
  pre32(mass, Ipre, tot);
  const float Itot = tot * dsv;
  float sigd[4];
  #pragma unroll
  for (int j=0;j<4;++j) sigd[j] = (bk[j]*Itot - Ipre[j]*dsv) / (psc + 1e-8f);

  const float cf2  = fmaxf(cl*cl, 0.01f);
  const float nudiv = 500000.0f*cf2, nuh = 100000.0f*cf2;

  float outu[4], outv[4], outT[4];
  #pragma unroll
  for (int j=0;j<4;++j){
    const float pfac = R*Tcv[j]*bk[j]/(bk[j]*psc + 1e-8f);
    const float pgfu = -dphidx[j] - pfac*dpsdx;
    const float pgfv = -dphidy[j] - pfac*dpsdy;
    const float adiab = R*Tcv[j]/(bk[j]*psc*F_CP + 1e-8f) * (sigd[j]*psc);
    outu[j] = -(ucv[j]*dudx[j] + vcv[j]*dudy[j]) - sigd[j]*vgu[j] + fcor*vcv[j] + pgfu
              + nuh*lapu[j] - 1e-5f*ucv[j] + nudiv*gdivx[j];
    outv[j] = -(ucv[j]*dvdx[j] + vcv[j]*dvdy[j]) - sigd[j]*vgv[j] - fcor*ucv[j] + pgfv
              + nuh*lapv[j] - 1e-5f*vcv[j] + nudiv*gdivy[j];
    outT[j] = -(ucv[j]*dTdx[j] + vcv[j]*dTdy[j]) - sigd[j]*vgT[j] + adiab + nuh*lapT[j];
  }
  *(float4*)&du[ic] = make_float4(outu[0],outu[1],outu[2],outu[3]);
  *(float4*)&dv[ic] = make_float4(outv[0],outv[1],outv[2],outv[3]);
  *(float4*)&dT[ic] = make_float4(outT[0],outT[1],outT[2],outT[3]);
  if (zl == 0) dps[col] = -Itot;
}

// -------------------- polar filter helpers --------------------
__device__ __forceinline__ void filter_band(int y, int& k0, int& k1, bool& keepmode) {
  float lat = -F_HPI + (y+0.5f)*F_DLAT;
  float cut = fmaxf(360.0f*cosf(lat), 1.0f);
  int M = (int)floorf(cut);
  keepmode = (M <= 179);
  k0 = keepmode ? 0 : (M+1);
  k1 = keepmode ? M : 360;
}

// -------------------- kernel 3: folded-DFT polar filter (R16 verbatim) ---
// R17's synthesis k-split REGRESSED (SD rows 4 apart per lane pair = 256B
// stride = same-bank conflicts 9.1e6 -> 2.3e7; VGPR 40->44). R16 is the
// measured local optimum: 182-thread fold/synthesis, per-k rotation chains.
#define FKMAX 180
__global__ __launch_bounds__(384, 4) void k_filter4b(
    float* __restrict__ du, float* __restrict__ dv, float* __restrict__ dT,
    float* __restrict__ dps, float* __restrict__ dq) {
  __shared__ __align__(16) float smem[8704];   // 34.816 KB

  const int tid = threadIdx.x;
  const int xcd = blockIdx.x & 7;
  const int s   = blockIdx.x >> 3;                 // 0..1171
  const int bid = ((s >> 2) * 8 + xcd) * 4 + (s & 3);
  if (bid >= 9360) return;

  if (bid >= 8640) {
    // ---------------- dpsdt filter path (720 blocks) ----------------
    float*  f  = smem;                          // [720]
    float2* tw = (float2*)(smem + 720);         // [720]
    float*  sc = smem + 720 + 1440;             // [184]
    float*  ss = sc + 184;
    const int row = bid - 8640;                 // 0..719 = b*360+y
    const int y = row % NY;
    float* base = dps + (size_t)row*NX;
    for (int t = tid; t < NX; t += 384) {
      float a = (float)t * TH;
      float sv, cv; sincosf(a, &sv, &cv);
      tw[t] = make_float2(cv, sv);
      f[t] = base[t];
    }
    int k0, k1; bool keepmode;
    filter_band(y, k0, k1, keepmode);
    const int nk = k1 - k0 + 1;
    __syncthreads();
    if (tid < nk) {
      const int k = k0 + tid;
      float ac=0.f, as=0.f; int idx=0;
      for (int xx=0; xx<NX; ++xx) {
        const float fv = f[xx];
        const float2 t2 = tw[idx];
        ac = fmaf(fv, t2.x, ac); as = fmaf(fv, t2.y, as);
        idx += k; if (idx >= NX) idx -= NX;
      }
      sc[tid]=ac; ss[tid]=as;
    }
    __syncthreads();
    if (tid < 360) {
      const int x0 = tid, x1 = tid + 360;
      const int t0 = (x0 * k0) % NX;
      const int t1 = (x1 * k0) % NX;
      float c0 = tw[t0].x, s0 = tw[t0].y;
      float c1 = tw[t1].x, s1 = tw[t1].y;
      const float dc0 = tw[x0].x, dn0 = tw[x0].y;
      const float dc1 = tw[x1].x, dn1 = tw[x1].y;
      float a0 = 0.f, a1 = 0.f;
      for (int kk = 0; kk < nk; ++kk) {
        const int k = k0 + kk;
        const float w = (k==0 || k==360) ? 1.0f : 2.0f;
        a0 = fmaf(sc[kk], w*c0, fmaf(ss[kk], w*s0, a0));
        a1 = fmaf(sc[kk], w*c1, fmaf(ss[kk], w*s1, a1));
        float n0 = c0*dc0 - s0*dn0; s0 = c0*dn0 + s0*dc0; c0 = n0;
        float n1 = c1*dc1 - s1*dn1; s1 = c1*dn1 + s1*dc1; c1 = n1;
      }
      const float inv = 1.0f/720.0f;
      float o0 = keepmode ? a0*inv : f[x0] - a0*inv;
      float o1 = keepmode ? a1*inv : f[x1] - a1*inv;
      o0 = fminf(fmaxf(o0, -0.5f), 0.5f);
      o1 = fminf(fmaxf(o1, -0.5f), 0.5f);
      base[x0] = o0;
      base[x1] = o1;
    }
    return;
  }

  // ---------------- field filter path (8640 blocks) ----------------
  float* S0p = smem + 0;       // [91][8]
  float* S0m = smem + 728;
  float* S2p = smem + 1456;
  float* S2m = smem + 2184;
  float* Q1a = smem + 2912;
  float* Q2a = smem + 3640;
  float* Q3a = smem + 4368;
  float* Q4a = smem + 5096;
  float (*SD)[8][2] = (float(*)[8][2])(smem + 5824);  // [180][8][2]

  // fused k_zero: each field block zeroes its 1920-float dq slice
  {
    float4* dqv = (float4*)dq + (size_t)bid * 480;
    const float4 z4 = make_float4(0.f,0.f,0.f,0.f);
    for (int t = tid; t < 480; t += 384) dqv[t] = z4;
  }

  const int zq   = bid & 3;
  const int rest = bid >> 2;
  const int by   = rest % (NB*NY);
  const int fld  = rest / (NB*NY);
  const int y = by % NY, b = by / NY;
  float* fptr = (fld==0)? du : (fld==1)? dv : dT;
  const float clipv = (fld==2)? 0.01f : 0.02f;
  float* base = fptr + ((size_t)(b*NY+y)*NX)*NZ + zq*8;

  int k0, k1; bool keep;
  filter_band(y, k0, k1, keep);

  // ---- load + fold4 + mirror-fold (tid<182: pair-slot p, z-half zh) ----
  if (tid < 182) {
    const int p  = tid % 91;
    const int zh = tid / 91;
    const bool hasm = (p >= 1 && p <= 89);
    const int xm = 180 - p;
    const float4 q0 = *(const float4*)(base + (size_t)(p      )*NZ + zh*4);
    const float4 q1 = *(const float4*)(base + (size_t)(p + 180)*NZ + zh*4);
    const float4 q2 = *(const float4*)(base + (size_t)(p + 360)*NZ + zh*4);
    const float4 q3 = *(const float4*)(base + (size_t)(p + 540)*NZ + zh*4);
    float4 m0 = make_float4(0,0,0,0), m1 = m0, m2 = m0, m3 = m0;
    if (hasm) {
      m0 = *(const float4*)(base + (size_t)(xm      )*NZ + zh*4);
      m1 = *(const float4*)(base + (size_t)(xm + 180)*NZ + zh*4);
      m2 = *(const float4*)(base + (size_t)(xm + 360)*NZ + zh*4);
      m3 = *(const float4*)(base + (size_t)(xm + 540)*NZ + zh*4);
    }
    const int o = p*8 + zh*4;
    #pragma unroll
    for (int j = 0; j < 4; ++j) {
      const float a0 = (j==0)?q0.x:(j==1)?q0.y:(j==2)?q0.z:q0.w;
      const float a1 = (j==0)?q1.x:(j==1)?q1.y:(j==2)?q1.z:q1.w;
      const float a2 = (j==0)?q2.x:(j==1)?q2.y:(j==2)?q2.z:q2.w;
      const float a3 = (j==0)?q3.x:(j==1)?q3.y:(j==2)?q3.z:q3.w;
      const float b0 = (j==0)?m0.x:(j==1)?m0.y:(j==2)?m0.z:m0.w;
      const float b1 = (j==0)?m1.x:(j==1)?m1.y:(j==2)?m1.z:m1.w;
      const float b2 = (j==0)?m2.x:(j==1)?m2.y:(j==2)?m2.z:m2.w;
      const float b3 = (j==0)?m3.x:(j==1)?m3.y:(j==2)?m3.z:m3.w;
      const float s0  = a0+a1+a2+a3, s2  = a0-a1+a2-a3, A  = a0-a2, B  = a1-a3;
      const float s0M = b0+b1+b2+b3, s2M = b0-b1+b2-b3, AM = b0-b2, BM = b1-b3;
      S0p[o+j] = s0 + s0M;  S0m[o+j] = s0 - s0M;
      S2p[o+j] = s2 + s2M;  S2m[o+j] = s2 - s2M;
      Q1a[o+j] = A - BM;    Q2a[o+j] = AM - B;
      Q3a[o+j] = AM + B;    Q4a[o+j] = A + BM;
    }
  }
  __syncthreads();

  // ---- analysis: thread = (ks 0..95, xq 0..3); one k, 8 z, 91 slots ----
  {
    const int xq = tid & 3;
    const int ks = tid >> 2;            // 0..95; waves 0-2 even-class, 3-5 odd
    const bool isodd = (ks >= 48);
    const int slot = isodd ? ks - 48 : ks;
    const int ke0 = k0 + (k0 & 1);      // first even >= k0
    const int ko0 = k0 | 1;             // first odd  >= k0
    const int kbase = isodd ? ko0 : ke0;
    const int cnt   = (k1 >= kbase) ? (((k1 - kbase) >> 1) + 1) : 0;
    const bool dual = (cnt > 48);
    int k, x0, xe; bool act;
    if (dual) { k = kbase + 2*(slot + 48*(xq>>1)); x0 = (xq&1)?46:0; xe = (xq&1)?91:46; act = (k <= k1); }
    else      { k = kbase + 2*slot; x0 = 23*xq; xe = (xq==3)?91:(x0+23); act = (slot < cnt); }

    float ac[8], as[8];
    #pragma unroll
    for (int j=0;j<8;++j){ ac[j]=0.f; as[j]=0.f; }

    if (act) {
      float dc, ds; sincosf((float)k * TH, &ds, &dc);
      float c, s;   sincosf((float)((k * x0) % 720) * TH, &s, &c);
      const int n = xe - x0;
      if (!isodd) {
        const int r = k & 3;
        const float* Pc = ((r == 0) ? S0p : S2m) + x0*8;
        const float* Ps = ((r == 0) ? S0m : S2p) + x0*8;
        #pragma unroll 4
        for (int i = 0; i < n; ++i) {
          const float4 c0 = *(const float4*)(Pc + i*8);
          const float4 c1 = *(const float4*)(Pc + i*8 + 4);
          const float4 s0v = *(const float4*)(Ps + i*8);
          const float4 s1v = *(const float4*)(Ps + i*8 + 4);
          ac[0]=fmaf(c0.x ,c,ac[0]); as[0]=fmaf(s0v.x,s,as[0]);
          ac[1]=fmaf(c0.y ,c,ac[1]); as[1]=fmaf(s0v.y,s,as[1]);
          ac[2]=fmaf(c0.z ,c,ac[2]); as[2]=fmaf(s0v.z,s,as[2]);
          ac[3]=fmaf(c0.w ,c,ac[3]); as[3]=fmaf(s0v.w,s,as[3]);
          ac[4]=fmaf(c1.x ,c,ac[4]); as[4]=fmaf(s1v.x,s,as[4]);
          ac[5]=fmaf(c1.y ,c,ac[5]); as[5]=fmaf(s1v.y,s,as[5]);
          ac[6]=fmaf(c1.z ,c,ac[6]); as[6]=fmaf(s1v.z,s,as[6]);
          ac[7]=fmaf(c1.w ,c,ac[7]); as[7]=fmaf(s1v.w,s,as[7]);
          const float nc = fmaf(c, dc, -s*ds);
          s = fmaf(s, dc, c*ds); c = nc;
        }
      } else {
        const float sg = ((k & 3) == 1) ? 1.0f : -1.0f;
        const float* p1 = Q1a + x0*8; const float* p2 = Q2a + x0*8;
        const float* p3 = Q3a + x0*8; const float* p4 = Q4a + x0*8;
        #pragma unroll 2
        for (int i = 0; i < n; ++i) {
          const float4 u10 = *(const float4*)(p1 + i*8);
          const float4 u11 = *(const float4*)(p1 + i*8 + 4);
          const float4 u20 = *(const float4*)(p2 + i*8);
          const float4 u21 = *(const float4*)(p2 + i*8 + 4);
          const float4 u30 = *(const float4*)(p3 + i*8);
          const float4 u31 = *(const float4*)(p3 + i*8 + 4);
          const float4 u40 = *(const float4*)(p4 + i*8);
          const float4 u41 = *(const float4*)(p4 + i*8 + 4);
          const float svs = sg*s, cvs = sg*c;
          ac[0]=fmaf(u10.x,c,fmaf(u20.x,svs,ac[0])); as[0]=fmaf(u30.x,cvs,fmaf(u40.x,s,as[0]));
          ac[1]=fmaf(u10.y,c,fmaf(u20.y,svs,ac[1])); as[1]=fmaf(u30.y,cvs,fmaf(u40.y,s,as[1]));
          ac[2]=fmaf(u10.z,c,fmaf(u20.z,svs,ac[2])); as[2]=fmaf(u30.z,cvs,fmaf(u40.z,s,as[2]));
          ac[3]=fmaf(u10.w,c,fmaf(u20.w,svs,ac[3])); as[3]=fmaf(u30.w,cvs,fmaf(u40.w,s,as[3]));
          ac[4]=fmaf(u11.x,c,fmaf(u21.x,svs,ac[4])); as[4]=fmaf(u31.x,cvs,fmaf(u41.x,s,as[4]));
          ac[5]=fmaf(u11.y,c,fmaf(u21.y,svs,ac[5])); as[5]=fmaf(u31.y,cvs,fmaf(u41.y,s,as[5]));
          ac[6]=fmaf(u11.z,c,fmaf(u21.z,svs,ac[6])); as[6]=fmaf(u31.z,cvs,fmaf(u41.z,s,as[6]));
          ac[7]=fmaf(u11.w,c,fmaf(u21.w,svs,ac[7])); as[7]=fmaf(u31.w,cvs,fmaf(u41.w,s,as[7]));
          const float nc = fmaf(c, dc, -s*ds);
          s = fmaf(s, dc, c*ds); c = nc;
        }
      }
    }
    // combine partial sums over the 4-lane xq group
    #pragma unroll
    for (int j=0;j<8;++j){
      ac[j] += __shfl_xor(ac[j], 1);
      as[j] += __shfl_xor(as[j], 1);
    }
    if (!dual) {
      #pragma unroll
      for (int j=0;j<8;++j){
        ac[j] += __shfl_xor(ac[j], 2);
        as[j] += __shfl_xor(as[j], 2);
      }
    }
    if (act && ((xq & (dual ? 1 : 3)) == 0)) {
      const float w = (k==0 || k==360) ? 1.0f : 2.0f;
      const int r = k - k0;
      *(float4*)&SD[r][0][0] = make_float4(w*ac[0], w*as[0], w*ac[1], w*as[1]);
      *(float4*)&SD[r][2][0] = make_float4(w*ac[2], w*as[2], w*ac[3], w*as[3]);
      *(float4*)&SD[r][4][0] = make_float4(w*ac[4], w*as[4], w*ac[5], w*as[5]);
      *(float4*)&SD[r][6][0] = make_float4(w*ac[6], w*as[6], w*ac[7], w*as[7]);
    }
  }
  __syncthreads();

  // ---- synthesis: thread = (pair p 0..90, zh 0..1) serves x=p and 180-p ----
  if (tid < 182) {
    const int p  = tid % 91;
    const int zh = tid / 91;
    const bool hasm = (p >= 1 && p <= 89);
    float lx0[4],lx1[4],lx2[4],lx3[4], lm0[4],lm1[4],lm2[4],lm3[4];
    #pragma unroll
    for (int j=0;j<4;++j){ lx0[j]=lx1[j]=lx2[j]=lx3[j]=0.f; lm0[j]=lm1[j]=lm2[j]=lm3[j]=0.f; }

    const int m4 = (4*p) % 720;
    float dstep_s, dstep_c; sincosf((float)m4 * TH, &dstep_s, &dstep_c);

    // even residues r=0,2: split cos/sin sums P,S
    #pragma unroll
    for (int ri = 0; ri < 2; ++ri) {
      const int r = ri*2;
      const float tau = (ri==0)? 1.0f : -1.0f;
      const int kst = k0 + ((r - (k0 & 3) + 4) & 3);
      if (kst > k1) continue;
      float P[4]={0,0,0,0}, S[4]={0,0,0,0};
      float sv, cv; sincosf((float)((kst * p) % 720) * TH, &sv, &cv);
      #pragma unroll 2
      for (int k = kst; k <= k1; k += 4) {
        const float4 d01 = *(const float4*)&SD[k - k0][zh*4 + 0][0];
        const float4 d23 = *(const float4*)&SD[k - k0][zh*4 + 2][0];
        P[0]=fmaf(d01.x,cv,P[0]); S[0]=fmaf(d01.y,sv,S[0]);
        P[1]=fmaf(d01.z,cv,P[1]); S[1]=fmaf(d01.w,sv,S[1]);
        P[2]=fmaf(d23.x,cv,P[2]); S[2]=fmaf(d23.y,sv,S[2]);
        P[3]=fmaf(d23.z,cv,P[3]); S[3]=fmaf(d23.w,sv,S[3]);
        float nc = fmaf(cv, dstep_c, -sv*dstep_s);   // forward +4p*theta
        float ns = fmaf(sv, dstep_c,  cv*dstep_s);
        cv = nc; sv = ns;
      }
      #pragma unroll
      for (int j=0;j<4;++j){
        const float hx = P[j] + S[j];
        const float hm = (ri==0) ? (P[j] - S[j]) : (S[j] - P[j]);
        lx0[j]+=hx; lx2[j]+=hx; lx1[j]+=tau*hx; lx3[j]+=tau*hx;
        lm0[j]+=hm; lm2[j]+=hm; lm1[j]+=tau*hm; lm3[j]+=tau*hm;
      }
    }
    // odd residues r=1,3: 4 split sums Cc,Cs,Sc,Ss
    #pragma unroll
    for (int ri = 0; ri < 2; ++ri) {
      const int r = ri*2 + 1;
      const float sig = (ri==0)? 1.0f : -1.0f;
      const int kst = k0 + ((r - (k0 & 3) + 4) & 3);
      if (kst > k1) continue;
      float Cc[4]={0,0,0,0}, Cs[4]={0,0,0,0}, Sc[4]={0,0,0,0}, Ss[4]={0,0,0,0};
      float sv, cv; sincosf((float)((kst * p) % 720) * TH, &sv, &cv);
      #pragma unroll 2
      for (int k = kst; k <= k1; k += 4) {
        const float4 d01 = *(const float4*)&SD[k - k0][zh*4 + 0][0];
        const float4 d23 = *(const float4*)&SD[k - k0][zh*4 + 2][0];
        Cc[0]=fmaf(d01.x,cv,Cc[0]); Cs[0]=fmaf(d01.x,sv,Cs[0]);
        Sc[0]=fmaf(d01.y,cv,Sc[0]); Ss[0]=fmaf(d01.y,sv,Ss[0]);
        Cc[1]=fmaf(d01.z,cv,Cc[1]); Cs[1]=fmaf(d01.z,sv,Cs[1]);
        Sc[1]=fmaf(d01.w,cv,Sc[1]); Ss[1]=fmaf(d01.w,sv,Ss[1]);
        Cc[2]=fmaf(d23.x,cv,Cc[2]); Cs[2]=fmaf(d23.x,sv,Cs[2]);
        Sc[2]=fmaf(d23.y,cv,Sc[2]); Ss[2]=fmaf(d23.y,sv,Ss[2]);
        Cc[3]=fmaf(d23.z,cv,Cc[3]); Cs[3]=fmaf(d23.z,sv,Cs[3]);
        Sc[3]=fmaf(d23.w,cv,Sc[3]); Ss[3]=fmaf(d23.w,sv,Ss[3]);
        float nc = fmaf(cv, dstep_c, -sv*dstep_s);
        float ns = fmaf(sv, dstep_c,  cv*dstep_s);
        cv = nc; sv = ns;
      }
      #pragma unroll
      for (int j=0;j<4;++j){
        const float hrx = Cc[j] + Ss[j];
        const float hix = Sc[j] - Cs[j];
        const float hrm = sig*(Cs[j] + Sc[j]);
        const float him = Ss[j] - Cc[j];
        lx0[j]+=hrx; lx2[j]-=hrx; lx1[j]+=sig*hix; lx3[j]-=sig*hix;
        lm0[j]+=hrm; lm2[j]-=hrm; lm1[j]+=him;     lm3[j]-=him;
      }
    }

    const float inv = 1.0f/720.0f;
    // recover original field values (subtract mode) from folded arrays
    float qx[4][4], qm[4][4];
    if (!keep) {
      const int o = p*8 + zh*4;
      #pragma unroll
      for (int j=0;j<4;++j){
        const float s0x = 0.5f*(S0p[o+j] + S0m[o+j]);
        const float s0M = 0.5f*(S0p[o+j] - S0m[o+j]);
        const float s2x = 0.5f*(S2p[o+j] + S2m[o+j]);
        const float s2M = 0.5f*(S2p[o+j] - S2m[o+j]);
        const float Ax  = 0.5f*(Q1a[o+j] + Q4a[o+j]);
        const float AM  = 0.5f*(Q2a[o+j] + Q3a[o+j]);
        const float Bx  = 0.5f*(Q3a[o+j] - Q2a[o+j]);
        const float BM  = 0.5f*(Q4a[o+j] - Q1a[o+j]);
        { const float sp = 0.25f*(s0x + s2x), sm = 0.25f*(s0x - s2x);
          qx[0][j] = sp + 0.5f*Ax; qx[1][j] = sm + 0.5f*Bx;
          qx[2][j] = sp - 0.5f*Ax; qx[3][j] = sm - 0.5f*Bx; }
        { const float sp = 0.25f*(s0M + s2M), sm = 0.25f*(s0M - s2M);
          qm[0][j] = sp + 0.5f*AM; qm[1][j] = sm + 0.5f*BM;
          qm[2][j] = sp - 0.5f*AM; qm[3][j] = sm - 0.5f*BM; }
      }
    }
    // x = p outputs
    {
      float o[4][4];
      #pragma unroll
      for (int j=0;j<4;++j){
        float l0 = lx0[j]*inv, l1 = lx1[j]*inv, l2 = lx2[j]*inv, l3 = lx3[j]*inv;
        if (!keep) { l0 = qx[0][j]-l0; l1 = qx[1][j]-l1; l2 = qx[2][j]-l2; l3 = qx[3][j]-l3; }
        o[0][j] = fminf(fmaxf(l0,-clipv),clipv);
        o[1][j] = fminf(fmaxf(l1,-clipv),clipv);
        o[2][j] = fminf(fmaxf(l2,-clipv),clipv);
        o[3][j] = fminf(fmaxf(l3,-clipv),clipv);
      }
      #pragma unroll
      for (int jj=0;jj<4;++jj)
        *(float4*)(base + (size_t)(p + 180*jj)*NZ + zh*4) =
            make_float4(o[jj][0], o[jj][1], o[jj][2], o[jj][3]);
    }
    // mirror x = 180-p outputs
    if (hasm) {
      const int xm = 180 - p;
      float o[4][4];
      #pragma unroll
      for (int j=0;j<4;++j){
        float l0 = lm0[j]*inv, l1 = lm1[j]*inv, l2 = lm2[j]*inv, l3 = lm3[j]*inv;
        if (!keep) { l0 = qm[0][j]-l0; l1 = qm[1][j]-l1; l2 = qm[2][j]-l2; l3 = qm[3][j]-l3; }
        o[0][j] = fminf(fmaxf(l0,-clipv),clipv);
        o[1][j] = fminf(fmaxf(l1,-clipv),clipv);
        o[2][j] = fminf(fmaxf(l2,-clipv),clipv);
        o[3][j] = fminf(fmaxf(l3,-clipv),clipv);
      }
      #pragma unroll
      for (int jj=0;jj<4;++jj)
        *(float4*)(base + (size_t)(xm + 180*jj)*NZ + zh*4) =
            make_float4(o[jj][0], o[jj][1], o[jj][2], o[jj][3]);
    }
  }
}

// -------------------- host --------------------
extern "C" void kernel_launch(void* const* d_in, const int* in_sizes, int n_in,
                              void* d_out, int out_size, void* d_ws, size_t ws_size,
                              hipStream_t stream) {
  (void)in_sizes; (void)n_in; (void)d_ws; (void)ws_size; (void)out_size;
  const float* u  = (const float*)d_in[0];
  const float* v  = (const float*)d_in[1];
  const float* T  = (const float*)d_in[2];
  const float* ps = (const float*)d_in[4];
  const float* Rp = (const float*)d_in[6];

  float* out = (float*)d_out;
  float* du  = out;
  float* dv  = out + (size_t)NPTS;
  float* dT  = out + (size_t)2*NPTS;
  float* dq  = out + (size_t)3*NPTS;   // staged as div_h scratch; zeroed in filter
  float* dps = out + (size_t)4*NPTS;

  k_divh<<<NPTS/(256*4), 256, 0, stream>>>(u, v, dq);
  k_tend<<<NCOL/32,      256, 0, stream>>>(u, v, T, ps, Rp, dq, du, dv, dT, dps);
  k_filter4b<<<9376, 384, 0, stream>>>(du, dv, dT, dps, dq);
}